// Round 1
// baseline (14.860 us; speedup 1.0000x reference)
//
#include <hip/hip_runtime.h>
#include <hip/hip_bf16.h>

// Fast Walsh-Hadamard Transform for 12 qubits (N=4096), batch=256, complex
// stored as separate real/imag planes. Reference computes H @ state with
// H = (H2)^{⊗12}; entries are ±1/64, so out = FWHT(x) / 64.
//
// Inputs: d_in[0] = state_real [256,4096,1] f32
//         d_in[1] = state_imag [256,4096,1] f32
//         d_in[2] = H [4096,4096] f32 (UNUSED — structure exploited)
// Output: d_out = [out_real (256*4096) | out_imag (256*4096)] f32

#define NQ 12
#define NN 4096            // 2^12
#define THREADS 1024       // 4 elements / thread

__global__ __launch_bounds__(THREADS)
void fwht_kernel(const float* __restrict__ xr,
                 const float* __restrict__ xi,
                 float* __restrict__ out) {
    __shared__ float s[NN];

    const int blk = blockIdx.x;              // 0..511: [0,256) real, [256,512) imag
    const int t   = threadIdx.x;

    const float* src = (blk < 256) ? (xr + (size_t)blk * NN)
                                   : (xi + (size_t)(blk - 256) * NN);
    float* dst = out + (size_t)blk * NN;     // real plane then imag plane, contiguous

    // ---- load: 4096 floats via 1024 float4 loads (fully coalesced) ----
    const float4* __restrict__ src4 = (const float4*)src;
    float4* s4 = (float4*)s;
    s4[t] = src4[t];
    __syncthreads();

    // ---- 12 butterfly stages in LDS ----
    // pairs p in [0, N/2); i = base of pair for given stride.
    // worst-case LDS aliasing is 2 lanes/bank (free on 32-bank wave64).
#pragma unroll
    for (int stage = 0; stage < NQ; ++stage) {
        const int stride = 1 << stage;
        const int lo_mask = stride - 1;
#pragma unroll
        for (int k = 0; k < (NN / 2) / THREADS; ++k) {   // 2 pairs / thread
            const int p = t + THREADS * k;
            const int i = ((p & ~lo_mask) << 1) | (p & lo_mask);
            const float a = s[i];
            const float b = s[i + stride];
            s[i]          = a + b;
            s[i + stride] = a - b;
        }
        __syncthreads();
    }

    // ---- scale by (1/sqrt(2))^12 = 1/64 and store ----
    const float scale = 0.015625f;
    float4 v = s4[t];
    v.x *= scale; v.y *= scale; v.z *= scale; v.w *= scale;
    ((float4*)dst)[t] = v;
}

extern "C" void kernel_launch(void* const* d_in, const int* in_sizes, int n_in,
                              void* d_out, int out_size, void* d_ws, size_t ws_size,
                              hipStream_t stream) {
    const float* xr = (const float*)d_in[0];
    const float* xi = (const float*)d_in[1];
    float* out = (float*)d_out;

    // 256 batches x {real, imag} = 512 independent 4096-point FWHTs
    fwht_kernel<<<512, THREADS, 0, stream>>>(xr, xi, out);
}

// Round 2
// 10.729 us; speedup vs baseline: 1.3850x; 1.3850x over previous
//
#include <hip/hip_runtime.h>
#include <hip/hip_bf16.h>

// FWHT for 12 qubits (N=4096), batch 256, real/imag planes.
// out = FWHT(x) / 64  (H = (H2)^{⊗12}, entries ±1/64).
//
// Radix-16: three rounds of in-register FWHT-16 over bit-groups
// [3:0], [7:4], [11:8], with two padded-LDS transpose exchanges.
// LDS pad: linear idx i stored at i + (i>>4)  (stride-17 rows) —
// every access phase is ≤2 lanes/bank (free on wave64/32-bank).

#define NN 4096
#define T  256            // threads/block, 16 elems/thread

__device__ __forceinline__ void fwht16(float x[16]) {
#pragma unroll
    for (int s = 0; s < 4; ++s) {
        const int st = 1 << s;
#pragma unroll
        for (int i = 0; i < 16; ++i) {
            if ((i & st) == 0) {
                const float a = x[i];
                const float b = x[i + st];
                x[i]      = a + b;
                x[i + st] = a - b;
            }
        }
    }
}

__global__ __launch_bounds__(T)
void fwht_kernel(const float* __restrict__ xr,
                 const float* __restrict__ xi,
                 float* __restrict__ out) {
    __shared__ float s[NN + NN / 16];   // 4352 floats = 17408 B

    const int blk = blockIdx.x;         // 0..511
    const int t   = threadIdx.x;        // 0..255

    const float* src = (blk < 256) ? (xr + (size_t)blk * NN)
                                   : (xi + (size_t)(blk - 256) * NN);
    float* dst = out + (size_t)blk * NN;

    float x[16];

    // ---- load: 16 contiguous floats per thread (4x dwordx4) ----
    const float4* src4 = (const float4*)(src + t * 16);
#pragma unroll
    for (int k = 0; k < 4; ++k) {
        const float4 v = src4[k];
        x[4 * k + 0] = v.x; x[4 * k + 1] = v.y;
        x[4 * k + 2] = v.z; x[4 * k + 3] = v.w;
    }

    // ---- Round A: FWHT-16 over bits [3:0] ----
    fwht16(x);

    // ---- exchange A->B: value (P,Q,r) at n = t*16+r, padded = t*17+r ----
#pragma unroll
    for (int r = 0; r < 16; ++r)
        s[t * 17 + r] = x[r];
    __syncthreads();

    // ---- Round B: gather over Q (bits [7:4]) at fixed (P = t>>4, R = t&15)
    //      n = P*256 + q*16 + R  ->  padded = P*272 + q*17 + R
    const int baseB = (t >> 4) * 272 + (t & 15);
#pragma unroll
    for (int q = 0; q < 16; ++q)
        x[q] = s[baseB + q * 17];

    fwht16(x);

    // write back to the SAME addresses this thread just read (no barrier
    // needed in between: read/write sets are thread-private)
#pragma unroll
    for (int q = 0; q < 16; ++q)
        s[baseB + q * 17] = x[q];
    __syncthreads();

    // ---- Round C: gather over P (bits [11:8]) at fixed (Q = t>>4, R = t&15)
    //      n = p*256 + Q*16 + R  ->  padded = p*272 + Q*17 + R
    const int baseC = (t >> 4) * 17 + (t & 15);
#pragma unroll
    for (int p = 0; p < 16; ++p)
        x[p] = s[baseC + p * 272];

    fwht16(x);

    // ---- scale by 1/64, store: n = p*256 + t (256B contiguous per instr) ----
    const float scale = 0.015625f;
#pragma unroll
    for (int p = 0; p < 16; ++p)
        dst[p * 256 + t] = x[p] * scale;
}

extern "C" void kernel_launch(void* const* d_in, const int* in_sizes, int n_in,
                              void* d_out, int out_size, void* d_ws, size_t ws_size,
                              hipStream_t stream) {
    const float* xr = (const float*)d_in[0];
    const float* xi = (const float*)d_in[1];
    float* out = (float*)d_out;

    fwht_kernel<<<512, T, 0, stream>>>(xr, xi, out);
}